// Round 1
// baseline (25.639 us; speedup 1.0000x reference)
//
#include <hip/hip_runtime.h>

// BiorUpSampling: 2x zero-interleaved upsample + separable 9-tap filter (W then H),
// SAME zero padding. Polyphase decomposition:
//   even output col 2c:  sum_m x[., c-2+m] * f[2m]      (5 taps E)
//   odd  output col 2c+1: sum_m x[., c-1+m] * f[2m+1]   (4 taps O)
// identically along rows. Filter is symmetric so conv-vs-corr is moot.

constexpr int H = 512, W = 512, BATCH = 16;
constexpr int RP = 8;        // input row-pairs (output row quads) per block
constexpr int RL = RP + 4;   // rows staged in LDS (2-row halo each side)
constexpr int TW = 520;      // tile width: cols -2..517 (518 used, pad to 520)

__global__ __launch_bounds__(256)
void bior_up_kernel(const float* __restrict__ in, float* __restrict__ out) {
  // E[m] = f[2m], O[m] = f[2m+1]
  constexpr float E0 =  0.03782845550699535f;
  constexpr float E1 = -0.1106244044184226f;
  constexpr float E2 =  0.8526986790094022f;
  constexpr float E3 = -0.1106244044184226f;
  constexpr float E4 =  0.03782845550699535f;
  constexpr float O0 = -0.02384946501937986f;
  constexpr float O1 =  0.3774028556126536f;
  constexpr float O2 =  0.3774028556126537f;
  constexpr float O3 = -0.02384946501937986f;

  __shared__ float tile[RL][TW];   // tile[i][j] = x[r0-2+i][j-2] (0 outside)

  const int tid = threadIdx.x;
  const int r0  = blockIdx.x * RP;       // first input row-pair of this block
  const int b   = blockIdx.y;
  const float* inb = in + (size_t)b * H * W;

  // ---- stage rows r0-2 .. r0+RP+1 into LDS, coalesced, zero-padded ----
  for (int i = 0; i < RL; ++i) {
    const int gr = r0 - 2 + i;
    const bool rv = ((unsigned)gr < (unsigned)H);
    const float* rowp = inb + (size_t)gr * W;
    for (int j = tid; j < TW; j += 256) {
      const int gc = j - 2;
      float v = 0.0f;
      if (rv && (unsigned)gc < (unsigned)W) v = rowp[gc];
      tile[i][j] = v;
    }
  }
  __syncthreads();

  // ---- horizontal polyphase filter, once per staged row ----
  // thread owns input cols c, c+1  ->  output cols 2c..2c+3  (c = 2*tid)
  const int c = 2 * tid;
  float A[RL], B[RL], C[RL], D[RL];
#pragma unroll
  for (int i = 0; i < RL; ++i) {
    const float v0 = tile[i][c + 0];   // x[c-2]
    const float v1 = tile[i][c + 1];   // x[c-1]
    const float v2 = tile[i][c + 2];   // x[c]
    const float v3 = tile[i][c + 3];   // x[c+1]
    const float v4 = tile[i][c + 4];   // x[c+2]
    const float v5 = tile[i][c + 5];   // x[c+3]
    A[i] = v0*E0 + v1*E1 + v2*E2 + v3*E3 + v4*E4;  // he(c)   -> out col 2c
    B[i] = v1*O0 + v2*O1 + v3*O2 + v4*O3;          // ho(c)   -> out col 2c+1
    C[i] = v1*E0 + v2*E1 + v3*E2 + v4*E3 + v5*E4;  // he(c+1) -> out col 2c+2
    D[i] = v2*O0 + v3*O1 + v4*O2 + v5*O3;          // ho(c+1) -> out col 2c+3
  }

  // ---- vertical polyphase filter + coalesced float4 stores ----
  float* outb = out + (size_t)b * (2 * H) * (2 * W);
#pragma unroll
  for (int p = 0; p < RP; ++p) {
    float4 ev, od;
    ev.x = A[p]*E0 + A[p+1]*E1 + A[p+2]*E2 + A[p+3]*E3 + A[p+4]*E4;
    ev.y = B[p]*E0 + B[p+1]*E1 + B[p+2]*E2 + B[p+3]*E3 + B[p+4]*E4;
    ev.z = C[p]*E0 + C[p+1]*E1 + C[p+2]*E2 + C[p+3]*E3 + C[p+4]*E4;
    ev.w = D[p]*E0 + D[p+1]*E1 + D[p+2]*E2 + D[p+3]*E3 + D[p+4]*E4;
    od.x = A[p+1]*O0 + A[p+2]*O1 + A[p+3]*O2 + A[p+4]*O3;
    od.y = B[p+1]*O0 + B[p+2]*O1 + B[p+3]*O2 + B[p+4]*O3;
    od.z = C[p+1]*O0 + C[p+2]*O1 + C[p+3]*O2 + C[p+4]*O3;
    od.w = D[p+1]*O0 + D[p+2]*O1 + D[p+3]*O2 + D[p+4]*O3;

    const int row_e = 2 * (r0 + p);
    *reinterpret_cast<float4*>(&outb[(size_t)row_e       * (2 * W) + 4 * tid]) = ev;
    *reinterpret_cast<float4*>(&outb[(size_t)(row_e + 1) * (2 * W) + 4 * tid]) = od;
  }
}

extern "C" void kernel_launch(void* const* d_in, const int* in_sizes, int n_in,
                              void* d_out, int out_size, void* d_ws, size_t ws_size,
                              hipStream_t stream) {
  const float* in = (const float*)d_in[0];
  float* out = (float*)d_out;
  dim3 grid(H / RP, BATCH);   // 64 x 16 = 1024 blocks
  bior_up_kernel<<<grid, 256, 0, stream>>>(in, out);
}

// Round 2
// 24.876 us; speedup vs baseline: 1.0307x; 1.0307x over previous
//
#include <hip/hip_runtime.h>

// BiorUpSampling: 2x zero-interleaved upsample + separable symmetric 9-tap
// filter (W then H), SAME zero padding. Polyphase form, register-only:
//   out[2r+pr, 2c+pc] = sum over a 5x5/5x4/4x5/4x4 input window.
// No LDS: each thread loads its 6-float horizontal window per row as three
// aligned float2s; column redundancy (3x) is served by L2/L3 (input = 16 MiB).

constexpr int H = 512, W = 512;
constexpr int RP = 8;        // input row-pairs per block -> 16 output rows
constexpr int RL = RP + 4;   // rows consumed (2-row halo each side)

__global__ __launch_bounds__(256)
void bior_up_kernel(const float* __restrict__ in, float* __restrict__ out) {
  // E[m] = f[2m] (even phase, 5 taps), O[m] = f[2m+1] (odd phase, 4 taps)
  constexpr float E0 =  0.03782845550699535f;
  constexpr float E1 = -0.1106244044184226f;
  constexpr float E2 =  0.8526986790094022f;
  constexpr float E3 = -0.1106244044184226f;
  constexpr float E4 =  0.03782845550699535f;
  constexpr float O0 = -0.02384946501937986f;
  constexpr float O1 =  0.3774028556126536f;
  constexpr float O2 =  0.3774028556126537f;
  constexpr float O3 = -0.02384946501937986f;

  const int tid = threadIdx.x;
  const int r0  = blockIdx.x * RP;       // first input row of this block's pairs
  const int b   = blockIdx.y;
  const float* inb = in + (size_t)b * H * W;

  const int c = 2 * tid;                 // this thread's input cols: c, c+1
  const bool lv = (c >= 2);              // cols c-2,c-1 in-bounds
  const bool rv = (c <= W - 4);          // cols c+2,c+3 in-bounds (c<=508)

  // Horizontal polyphase per row, results in registers:
  //   A=he(c) -> out col 2c, B=ho(c) -> 2c+1, C=he(c+1) -> 2c+2, D=ho(c+1) -> 2c+3
  float A[RL], B[RL], C[RL], D[RL];
#pragma unroll
  for (int i = 0; i < RL; ++i) {
    const int gr = r0 - 2 + i;
    const bool rowv = ((unsigned)gr < (unsigned)H);
    const float* rowp = inb + (size_t)gr * W;
    const float2 z = make_float2(0.0f, 0.0f);
    const float2 L = (rowv && lv) ? *reinterpret_cast<const float2*>(rowp + c - 2) : z;
    const float2 M =  rowv        ? *reinterpret_cast<const float2*>(rowp + c)     : z;
    const float2 R = (rowv && rv) ? *reinterpret_cast<const float2*>(rowp + c + 2) : z;
    const float v0 = L.x, v1 = L.y, v2 = M.x, v3 = M.y, v4 = R.x, v5 = R.y;
    A[i] = v0*E0 + v1*E1 + v2*E2 + v3*E3 + v4*E4;
    B[i] = v1*O0 + v2*O1 + v3*O2 + v4*O3;
    C[i] = v1*E0 + v2*E1 + v3*E2 + v4*E3 + v5*E4;
    D[i] = v2*O0 + v3*O1 + v4*O2 + v5*O3;
  }

  // Vertical polyphase + coalesced float4 stores (block covers the full row).
  float* outb = out + (size_t)b * (2 * H) * (2 * W);
#pragma unroll
  for (int p = 0; p < RP; ++p) {
    float4 ev, od;
    ev.x = A[p]*E0 + A[p+1]*E1 + A[p+2]*E2 + A[p+3]*E3 + A[p+4]*E4;
    ev.y = B[p]*E0 + B[p+1]*E1 + B[p+2]*E2 + B[p+3]*E3 + B[p+4]*E4;
    ev.z = C[p]*E0 + C[p+1]*E1 + C[p+2]*E2 + C[p+3]*E3 + C[p+4]*E4;
    ev.w = D[p]*E0 + D[p+1]*E1 + D[p+2]*E2 + D[p+3]*E3 + D[p+4]*E4;
    od.x = A[p+1]*O0 + A[p+2]*O1 + A[p+3]*O2 + A[p+4]*O3;
    od.y = B[p+1]*O0 + B[p+2]*O1 + B[p+3]*O2 + B[p+4]*O3;
    od.z = C[p+1]*O0 + C[p+2]*O1 + C[p+3]*O2 + C[p+4]*O3;
    od.w = D[p+1]*O0 + D[p+2]*O1 + D[p+3]*O2 + D[p+4]*O3;

    const int row_e = 2 * (r0 + p);
    *reinterpret_cast<float4*>(&outb[(size_t)row_e       * (2 * W) + 4 * tid]) = ev;
    *reinterpret_cast<float4*>(&outb[(size_t)(row_e + 1) * (2 * W) + 4 * tid]) = od;
  }
}

extern "C" void kernel_launch(void* const* d_in, const int* in_sizes, int n_in,
                              void* d_out, int out_size, void* d_ws, size_t ws_size,
                              hipStream_t stream) {
  const float* in = (const float*)d_in[0];
  float* out = (float*)d_out;
  const int batch = in_sizes[0] / (H * W);
  dim3 grid(H / RP, batch);   // 64 x 16 = 1024 blocks
  bior_up_kernel<<<grid, 256, 0, stream>>>(in, out);
}

// Round 4
// 20.228 us; speedup vs baseline: 1.2675x; 1.2298x over previous
//
#include <hip/hip_runtime.h>

// BiorUpSampling: 2x zero-interleaved upsample + separable symmetric 9-tap
// filter, SAME zero padding. Polyphase, register-streaming:
// even out col 2c: 5 taps E over x[c-2..c+2]; odd col 2c+1: 4 taps O over x[c-1..c+2];
// same along rows. Vertical filter uses a 5-row ring buffer so loads and
// stores interleave steadily and register pressure stays low (occupancy up).

constexpr int H = 512, W = 512;
constexpr int RP = 8;   // input rows advanced per block -> 16 output rows

typedef float f32x4 __attribute__((ext_vector_type(4)));

__global__ __launch_bounds__(256)
void bior_up_kernel(const float* __restrict__ in, float* __restrict__ out) {
  constexpr float E0 =  0.03782845550699535f;
  constexpr float E1 = -0.1106244044184226f;
  constexpr float E2 =  0.8526986790094022f;
  constexpr float E3 = -0.1106244044184226f;
  constexpr float E4 =  0.03782845550699535f;
  constexpr float O0 = -0.02384946501937986f;
  constexpr float O1 =  0.3774028556126536f;
  constexpr float O2 =  0.3774028556126537f;
  constexpr float O3 = -0.02384946501937986f;

  const int tid = threadIdx.x;
  const int r0  = blockIdx.x * RP;
  const int b   = blockIdx.y;
  const float* inb  = in  + (size_t)b * H * W;
  float*       outb = out + (size_t)b * (2 * H) * (2 * W);

  const int c = 2 * tid;              // this thread's input cols: c, c+1
  const bool lv = (c >= 2);
  const bool rv = (c <= W - 4);

  // Ring of horizontally-filtered rows. Slot k holds row (current_gr - 4 + k).
  // A=he(c)->out 2c, B=ho(c)->2c+1, C=he(c+1)->2c+2, D=ho(c+1)->2c+3
  float A[5], B[5], C[5], D[5];

#define HROW(GR, AI, BI, CI, DI)                                              \
  {                                                                           \
    const int _gr = (GR);                                                     \
    const bool rowv = ((unsigned)_gr < (unsigned)H);                          \
    const float* rowp = inb + (size_t)_gr * W;                                \
    const float2 z = make_float2(0.0f, 0.0f);                                 \
    const float2 Lq = (rowv && lv) ? *reinterpret_cast<const float2*>(rowp + c - 2) : z; \
    const float2 Mq =  rowv        ? *reinterpret_cast<const float2*>(rowp + c)     : z; \
    const float2 Rq = (rowv && rv) ? *reinterpret_cast<const float2*>(rowp + c + 2) : z; \
    const float v0 = Lq.x, v1 = Lq.y, v2 = Mq.x, v3 = Mq.y, v4 = Rq.x, v5 = Rq.y; \
    AI = v0*E0 + v1*E1 + v2*E2 + v3*E3 + v4*E4;                               \
    BI = v1*O0 + v2*O1 + v3*O2 + v4*O3;                                       \
    CI = v1*E0 + v2*E1 + v3*E2 + v4*E3 + v5*E4;                               \
    DI = v2*O0 + v3*O1 + v4*O2 + v5*O3;                                       \
  }

  // Prologue: rows r0-2 .. r0+1 into slots 0..3.
  HROW(r0 - 2, A[0], B[0], C[0], D[0]);
  HROW(r0 - 1, A[1], B[1], C[1], D[1]);
  HROW(r0    , A[2], B[2], C[2], D[2]);
  HROW(r0 + 1, A[3], B[3], C[3], D[3]);

#pragma unroll
  for (int p = 0; p < RP; ++p) {
    // Load + h-filter row r0+2+p into slot 4; ring now holds rows rr-2..rr+2
    // for center rr = r0+p.
    HROW(r0 + 2 + p, A[4], B[4], C[4], D[4]);

    f32x4 ev, od;
    ev.x = A[0]*E0 + A[1]*E1 + A[2]*E2 + A[3]*E3 + A[4]*E4;
    ev.y = B[0]*E0 + B[1]*E1 + B[2]*E2 + B[3]*E3 + B[4]*E4;
    ev.z = C[0]*E0 + C[1]*E1 + C[2]*E2 + C[3]*E3 + C[4]*E4;
    ev.w = D[0]*E0 + D[1]*E1 + D[2]*E2 + D[3]*E3 + D[4]*E4;
    od.x = A[1]*O0 + A[2]*O1 + A[3]*O2 + A[4]*O3;
    od.y = B[1]*O0 + B[2]*O1 + B[3]*O2 + B[4]*O3;
    od.z = C[1]*O0 + C[2]*O1 + C[3]*O2 + C[4]*O3;
    od.w = D[1]*O0 + D[2]*O1 + D[3]*O2 + D[4]*O3;

    const int row_e = 2 * (r0 + p);
    f32x4* pe = reinterpret_cast<f32x4*>(&outb[(size_t)row_e       * (2 * W) + 4 * tid]);
    f32x4* po = reinterpret_cast<f32x4*>(&outb[(size_t)(row_e + 1) * (2 * W) + 4 * tid]);
    __builtin_nontemporal_store(ev, pe);   // output is write-once: keep L2 for input
    __builtin_nontemporal_store(od, po);

    // Shift ring (fully unrolled loop -> compiler renames, no real moves).
#pragma unroll
    for (int k = 0; k < 4; ++k) {
      A[k] = A[k + 1]; B[k] = B[k + 1]; C[k] = C[k + 1]; D[k] = D[k + 1];
    }
  }
#undef HROW
}

extern "C" void kernel_launch(void* const* d_in, const int* in_sizes, int n_in,
                              void* d_out, int out_size, void* d_ws, size_t ws_size,
                              hipStream_t stream) {
  const float* in = (const float*)d_in[0];
  float* out = (float*)d_out;
  const int batch = in_sizes[0] / (H * W);
  dim3 grid(H / RP, batch);   // 64 x 16 = 1024 blocks
  bior_up_kernel<<<grid, 256, 0, stream>>>(in, out);
}